// Round 1
// baseline (612.891 us; speedup 1.0000x reference)
//
#include <hip/hip_runtime.h>

typedef unsigned short u16;
typedef unsigned int u32;
typedef __attribute__((ext_vector_type(8))) __bf16 bf16x8;
typedef __attribute__((ext_vector_type(8))) unsigned short ushort8;
typedef __attribute__((ext_vector_type(4))) float f32x4;

// Exact RNE fp32 -> bf16 (no NaN inputs here). Exact for values with <=8 mantissa bits.
__device__ __forceinline__ u16 f32_to_bf16(float f) {
  u32 u = __float_as_uint(f);
  u = (u + 0x7fffu + ((u >> 16) & 1u)) >> 16;
  return (u16)u;
}

// ---------------- x: fp32 -> bf16, 8 elems/thread ----------------
__global__ void cvt_x_bf16(const float* __restrict__ x, u16* __restrict__ o, long n8) {
  long i = (long)blockIdx.x * blockDim.x + threadIdx.x;
  if (i >= n8) return;
  const float4* p = (const float4*)x + i * 2;
  float4 a = p[0], b = p[1];
  ushort8 v;
  v[0] = f32_to_bf16(a.x); v[1] = f32_to_bf16(a.y);
  v[2] = f32_to_bf16(a.z); v[3] = f32_to_bf16(a.w);
  v[4] = f32_to_bf16(b.x); v[5] = f32_to_bf16(b.y);
  v[6] = f32_to_bf16(b.z); v[7] = f32_to_bf16(b.w);
  *(ushort8*)(o + i * 8) = v;
}

// ---------------- weight dequant: w' = q_e2m1(wb/sb) * q_e4m3(ratio) ----------------
// w_dq = w' * gscale; gscale folded into GEMM epilogue. w' is EXACT in bf16
// (<=2 sig bits * <=4 sig bits = <=6 sig bits). One thread per 16-elem block.
__global__ void dequant_w(const float* __restrict__ w, const float* __restrict__ pba,
                          const float* __restrict__ gp, u16* __restrict__ wq, int nblk) {
  int i = blockIdx.x * blockDim.x + threadIdx.x;
  if (i >= nblk) return;
  float g = *gp;
  float gscale = g / 2688.0f;                   // global_amax / (6*448), fp32 like ref
  float ratio = (pba[i] / 6.0f) / gscale;       // = blk_scale_f / gscale
  ratio = fminf(fmaxf(ratio, 0.0f), 448.0f);    // ref clips to E4M3_MAX
  // e4m3 RNE quant: e = clip(floor(log2 ax), -6, 8) via exact bit-exponent
  int e = (int)((__float_as_uint(ratio) >> 23) & 0xffu) - 127;
  if (e < -6) e = -6;                           // ax<=448 => e<=8 already
  float stp = __uint_as_float((u32)(e - 3 + 127) << 23);  // 2^(e-3), exact
  float e4 = rintf(ratio / stp) * stp;          // q_e4m3 value (RNE, exact pow2 scaling)
  float sb = e4 * gscale;                       // ref blk_scale
  float den = fmaxf(sb, 1e-30f);
  bool pos = sb > 0.0f;

  const float4* wp = (const float4*)(w + (size_t)i * 16);
  float vals[16];
#pragma unroll
  for (int t = 0; t < 4; ++t) {
    float4 v = wp[t];
    vals[4 * t + 0] = v.x; vals[4 * t + 1] = v.y;
    vals[4 * t + 2] = v.z; vals[4 * t + 3] = v.w;
  }
  ushort8 o0, o1;
#pragma unroll
  for (int k = 0; k < 16; ++k) {
    float wv = pos ? vals[k] / den : 0.0f;      // true IEEE div, matches ref
    float s = (wv < 0.0f) ? -1.0f : 1.0f;
    float ax = fminf(fabsf(wv), 6.0f);          // clip to E2M1_MAX
    // e2m1 grid: half-step h = 2^clip(floor(log2 ax),0,2) / 2
    float h = ax < 2.0f ? 0.5f : (ax < 4.0f ? 1.0f : 2.0f);
    float q = rintf(ax / h) * h;                // RNE on the e2m1 grid
    u16 r = f32_to_bf16(s * q * e4);            // exact in bf16
    if (k < 8) o0[k] = r; else o1[k - 8] = r;
  }
  ushort8* dst = (ushort8*)(wq + (size_t)i * 16);
  dst[0] = o0; dst[1] = o1;
}

// ---------------- GEMM: C[M,N] = gscale * A[M,K] . B[N,K]^T, bf16 -> fp32 ----------------
// m97 structure: 128x128 tile, BK=32, 4 waves in 2x2, 4x4 16x16x32 MFMA per wave,
// global_load_lds width=16 staging, unpadded 128x32 LDS tiles, 2-barrier K-loop.
#define GLL16(gp_, lp_)                                              \
  __builtin_amdgcn_global_load_lds(                                  \
      (__attribute__((address_space(1))) void*)(gp_),                \
      (__attribute__((address_space(3))) void*)(lp_), 16, 0, 0)

__global__ __launch_bounds__(256) void gemm_bt(
    const u16* __restrict__ A, const u16* __restrict__ B,
    float* __restrict__ C, const float* __restrict__ gp,
    int M, int N, int K) {
  __shared__ u16 sA[128 * 32];   // 8 KB
  __shared__ u16 sB[128 * 32];   // 8 KB
  const int tid = threadIdx.x;
  const int lane = tid & 63;
  const int wave = tid >> 6;
  const int m0 = blockIdx.y * 128;
  const int n0 = blockIdx.x * 128;

  f32x4 zero = {0.0f, 0.0f, 0.0f, 0.0f};
  f32x4 acc[4][4];
#pragma unroll
  for (int i = 0; i < 4; ++i)
#pragma unroll
    for (int j = 0; j < 4; ++j) acc[i][j] = zero;

  // staging: wave w stages rows [w*32, w*32+32) of both tiles; lane i -> row i/4, col (i%4)*8
  // => LDS bytes land at (uniform base) + lane*16, matching HW scatter rule.
  const int srow = wave * 32 + (lane >> 2);
  const int scol = (lane & 3) * 8;
  const u16* gA = A + (size_t)(m0 + srow) * K + scol;
  const u16* gB = B + (size_t)(n0 + srow) * K + scol;
  u16* lA0 = &sA[(wave * 32) * 32];
  u16* lA1 = &sA[(wave * 32 + 16) * 32];
  u16* lB0 = &sB[(wave * 32) * 32];
  u16* lB1 = &sB[(wave * 32 + 16) * 32];
  const size_t rstep = (size_t)16 * K;

  // fragment addressing: lane holds X[row = lane&15][k = (lane>>4)*8 .. +8]
  const int fr = lane & 15;
  const int fq = (lane >> 4) * 8;
  const int wm = (wave >> 1) * 64;
  const int wn = (wave & 1) * 64;

  for (int k0 = 0; k0 < K; k0 += 32) {
    __syncthreads();                 // prev iter done reading LDS
    GLL16(gA + k0, lA0);
    GLL16(gA + k0 + rstep, lA1);
    GLL16(gB + k0, lB0);
    GLL16(gB + k0 + rstep, lB1);
    __syncthreads();                 // drains vmcnt(0): staged data visible

    bf16x8 af[4], bfr[4];
#pragma unroll
    for (int i = 0; i < 4; ++i)
      af[i] = *(const bf16x8*)&sA[(wm + i * 16 + fr) * 32 + fq];
#pragma unroll
    for (int j = 0; j < 4; ++j)
      bfr[j] = *(const bf16x8*)&sB[(wn + j * 16 + fr) * 32 + fq];
#pragma unroll
    for (int i = 0; i < 4; ++i)
#pragma unroll
      for (int j = 0; j < 4; ++j)
        acc[i][j] = __builtin_amdgcn_mfma_f32_16x16x32_bf16(af[i], bfr[j], acc[i][j], 0, 0, 0);
  }

  // epilogue: C/D layout col=lane&15, row=(lane>>4)*4+reg (m89/m91-verified)
  const float gs = (*gp) / 2688.0f;
  const int crow = m0 + wm + (lane >> 4) * 4;
  const int ccol = n0 + wn + (lane & 15);
#pragma unroll
  for (int i = 0; i < 4; ++i)
#pragma unroll
    for (int r = 0; r < 4; ++r) {
      float* cp = C + (size_t)(crow + i * 16 + r) * N + ccol;
#pragma unroll
      for (int j = 0; j < 4; ++j)
        cp[j * 16] = acc[i][j][r] * gs;
    }
}

extern "C" void kernel_launch(void* const* d_in, const int* in_sizes, int n_in,
                              void* d_out, int out_size, void* d_ws, size_t ws_size,
                              hipStream_t stream) {
  const float* x   = (const float*)d_in[0];   // (T, I) fp32
  const float* w   = (const float*)d_in[1];   // (O, I) fp32
  const float* pba = (const float*)d_in[2];   // (O, I/16) fp32
  const float* gam = (const float*)d_in[3];   // scalar fp32
  float* out = (float*)d_out;                 // (T, O) fp32

  const int T = 8192, I = 4096, O = 4096;
  u16* xb = (u16*)d_ws;                       // T*I bf16 = 64 MB
  u16* wb = xb + (size_t)T * I;               // O*I bf16 = 32 MB

  long n8 = (long)T * I / 8;
  hipLaunchKernelGGL(cvt_x_bf16, dim3((unsigned)((n8 + 255) / 256)), dim3(256), 0, stream,
                     x, xb, n8);
  int nblk = O * (I / 16);
  hipLaunchKernelGGL(dequant_w, dim3(nblk / 256), dim3(256), 0, stream,
                     w, pba, gam, wb, nblk);
  hipLaunchKernelGGL(gemm_bt, dim3(O / 128, T / 128), dim3(256), 0, stream,
                     xb, wb, out, gam, T, O, I);
}